// Round 4
// baseline (4132.014 us; speedup 1.0000x reference)
//
#include <hip/hip_runtime.h>
#include <hip/hip_bf16.h>

#define N_      100000
#define E_      1600000
#define G_      512
#define H_      128
#define T_      10
#define BN_EPS  1e-5f

#define NB_     782        // dst buckets of 128 nodes: ceil(100000/128)
#define NBLK_   200        // edge-chunk blocks for hist/scatter (8000 edges each)
#define ECHUNK_ 8000
#define NTILES_ 1563       // ceil(N/64) gemm row tiles
#define GRID_   768        // persistent network kernel grid (3 blocks/CU proven resident)
#define SCANN_  256400     // concat scan length: N_ (node counts) + NB_*NBLK_ (bucket matrix)
#define SCANB_  251        // ceil(SCANN_/1024)

typedef __attribute__((ext_vector_type(8))) short short8;
typedef __attribute__((ext_vector_type(4))) float floatx4;

__device__ __forceinline__ float bf2f(short s) {
    return __uint_as_float(((unsigned int)(unsigned short)s) << 16);
}
__device__ __forceinline__ short f2bf(float f) {
    unsigned int u = __float_as_uint(f);
    u += 0x7fffu + ((u >> 16) & 1u);          // round-to-nearest-even
    return (short)(u >> 16);
}

// ---------------------------------------------------------------------------
// prep: convert weights to bf16 W^T + per-graph node counts + exact per-node
// in-degree histogram (X[0..N)) + per-(bucket,block) coarse histogram
// (X[N_ + b*NBLK_ + blk]).  grid = NBLK_ x 256.
// ---------------------------------------------------------------------------
__global__ __launch_bounds__(256) void prep(
    const float* __restrict__ Wa, const float* __restrict__ Wb,
    short* __restrict__ Wt, const int* __restrict__ batch,
    float* __restrict__ cntf, const int* __restrict__ edst,
    int* __restrict__ X)
{
    __shared__ int hist[NB_];
    const int t = threadIdx.x, blk = blockIdx.x;
    for (int i = t; i < NB_; i += 256) hist[i] = 0;

    const int gtid = blk * 256 + t;              // 51200 threads total
    // convert W (8 mats of 128x128): Wt[mat][n*128+k] = bf16(W[mat][k*128+n])
    for (int i = gtid; i < 8 * 16384; i += NBLK_ * 256) {
        int mat = i >> 14;
        int rem = i & 16383;
        int k = rem >> 7;
        int n = rem & 127;
        const float* W = (mat < 4) ? (Wa + (size_t)mat * 16384)
                                   : (Wb + (size_t)(mat - 4) * 16384);
        Wt[(size_t)mat * 16384 + n * 128 + k] = f2bf(W[k * 128 + n]);
    }
    // per-graph node counts
    for (int i = gtid; i < N_; i += NBLK_ * 256)
        atomicAdd(&cntf[batch[i]], 1.0f);
    __syncthreads();
    // edge histograms
    const int base = blk * ECHUNK_;
    for (int i = base + t; i < base + ECHUNK_; i += 256) {
        int d = edst[i];
        atomicAdd(&X[d], 1);                     // exact per-node count
        atomicAdd(&hist[d >> 7], 1);             // coarse bucket count (LDS)
    }
    __syncthreads();
    for (int b = t; b < NB_; b += 256)
        X[N_ + b * NBLK_ + blk] = hist[b];
}

// ---------------------------------------------------------------------------
// scan_all: exclusive scan of X[0..SCANN_) -> Y, single kernel (in-kernel join;
// all SCANB_=251 blocks are co-resident on 256 CUs).  Y[N_] == E_ afterwards.
// ---------------------------------------------------------------------------
__global__ __launch_bounds__(256) void scan_all(
    const int* __restrict__ X, int* __restrict__ Y,
    int* __restrict__ bsum, int* __restrict__ barr)
{
    __shared__ int sd[256];
    __shared__ int ticket;
    const int t = threadIdx.x, blk = blockIdx.x;
    const int base = blk * 1024 + t * 4;

    int c0 = (base + 0 < SCANN_) ? X[base + 0] : 0;
    int c1 = (base + 1 < SCANN_) ? X[base + 1] : 0;
    int c2 = (base + 2 < SCANN_) ? X[base + 2] : 0;
    int c3 = (base + 3 < SCANN_) ? X[base + 3] : 0;
    int s = c0 + c1 + c2 + c3;
    sd[t] = s;
    __syncthreads();
    for (int d = 1; d < 256; d <<= 1) {
        int v = (t >= d) ? sd[t - d] : 0;
        __syncthreads();
        sd[t] += v;
        __syncthreads();
    }
    int pfx = sd[t] - s;
    if (base + 0 < SCANN_) Y[base + 0] = pfx;
    if (base + 1 < SCANN_) Y[base + 1] = pfx + c0;
    if (base + 2 < SCANN_) Y[base + 2] = pfx + c0 + c1;
    if (base + 3 < SCANN_) Y[base + 3] = pfx + c0 + c1 + c2;
    if (t == 255) bsum[blk] = sd[255];

    __threadfence();
    if (t == 0)
        ticket = __hip_atomic_fetch_add(&barr[60], 1, __ATOMIC_ACQ_REL,
                                        __HIP_MEMORY_SCOPE_AGENT);
    __syncthreads();
    if (ticket == gridDim.x - 1) {               // last-arriving block scans bsum
        int v0 = (t < SCANB_) ? bsum[t] : 0;
        sd[t] = v0;
        __syncthreads();
        for (int d = 1; d < 256; d <<= 1) {
            int v = (t >= d) ? sd[t - d] : 0;
            __syncthreads();
            sd[t] += v;
            __syncthreads();
        }
        if (t < SCANB_) bsum[t] = sd[t] - v0;
        __threadfence();
        __syncthreads();
        if (t == 0)
            __hip_atomic_store(&barr[61], 1, __ATOMIC_RELEASE,
                               __HIP_MEMORY_SCOPE_AGENT);
    }
    if (t == 0) {
        while (__hip_atomic_load(&barr[61], __ATOMIC_ACQUIRE,
                                 __HIP_MEMORY_SCOPE_AGENT) == 0)
            __builtin_amdgcn_s_sleep(8);
    }
    __syncthreads();
    int add = bsum[blk];
    if (base + 0 < SCANN_) Y[base + 0] += add;
    if (base + 1 < SCANN_) Y[base + 1] += add;
    if (base + 2 < SCANN_) Y[base + 2] += add;
    if (base + 3 < SCANN_) Y[base + 3] += add;
}

// ---------------------------------------------------------------------------
// scatter_csr: phase 1 (blocks < NBLK_): scatter edges into bucket-grouped
// ebuf via LDS cursors.  In-kernel barrier (all NB_ blocks resident).
// phase 2 (all NB_ blocks): bucket b -> exact CSR eidx; each block's writes
// are confined to its bucket's contiguous region (no write amplification).
// ---------------------------------------------------------------------------
__global__ __launch_bounds__(256) void scatter_csr(
    const int* __restrict__ esrc, const int* __restrict__ edst,
    const int* __restrict__ Y, int2* __restrict__ ebuf,
    int* __restrict__ eidx, int* __restrict__ barr)
{
    __shared__ int sbuf[NB_];
    const int t = threadIdx.x, blk = blockIdx.x;

    if (blk < NBLK_) {
        for (int b = t; b < NB_; b += 256)
            sbuf[b] = Y[N_ + b * NBLK_ + blk] - E_;
        __syncthreads();
        const int base = blk * ECHUNK_;
        for (int i = base + t; i < base + ECHUNK_; i += 256) {
            int s = esrc[i], d = edst[i];
            int pos = atomicAdd(&sbuf[d >> 7], 1);
            ebuf[pos] = make_int2(s, d);
        }
    }
    __syncthreads();
    __threadfence();
    if (t == 0) {
        int tk = __hip_atomic_fetch_add(&barr[62], 1, __ATOMIC_ACQ_REL,
                                        __HIP_MEMORY_SCOPE_AGENT);
        if (tk == gridDim.x - 1)
            __hip_atomic_store(&barr[63], 1, __ATOMIC_RELEASE,
                               __HIP_MEMORY_SCOPE_AGENT);
        else
            while (__hip_atomic_load(&barr[63], __ATOMIC_ACQUIRE,
                                     __HIP_MEMORY_SCOPE_AGENT) == 0)
                __builtin_amdgcn_s_sleep(8);
    }
    __syncthreads();

    const int b = blk;
    const int nodeBase = b << 7;
    if (t < 128) {
        int node = nodeBase + t;
        sbuf[t] = (node < N_) ? Y[node] : 0;
    }
    __syncthreads();
    int bstart = Y[N_ + b * NBLK_] - E_;
    int bend = (b == NB_ - 1) ? E_ : Y[N_ + (b + 1) * NBLK_] - E_;
    for (int i = bstart + t; i < bend; i += 256) {
        int2 e = ebuf[i];
        int pos = atomicAdd(&sbuf[e.y & 127], 1);
        eidx[pos] = e.x;
    }
}

// ---------------------------------------------------------------------------
// Persistent network kernel: all 8 GEMMs, BN stats/apply, aggregation, pooling
// and the output head in ONE launch, separated by device-scope grid barriers.
// grid = GRID_(768) blocks x 256; __launch_bounds__(256,3) + 36KB LDS
// guarantees full co-residency (LDS: 4 blk/CU, VGPR<=170: 3 blk/CU).
// ---------------------------------------------------------------------------
struct GinParams {
    const float* x;
    const int*   batch;
    const short* Wt;
    const float* ba; const float* ga; const float* bea;
    const float* bb; const float* gb; const float* beb;
    const float* Wl; const float* bl; const float* eps;
    const int* off; const int* eidx;
    short* P; short* Q; short* R;
    float* stats;            // 8 x 256
    float* pooled;           // 4 x G x 128
    const float* cntf;
    int* barr;
    float* out;
};

__device__ __forceinline__ void gbar(int* barr, int idx, int nblocks)
{
    __syncthreads();
    if (threadIdx.x == 0) {
        __threadfence();
        int* arrive = &barr[idx * 2];
        int* flag   = &barr[idx * 2 + 1];
        int t = __hip_atomic_fetch_add(arrive, 1, __ATOMIC_ACQ_REL,
                                       __HIP_MEMORY_SCOPE_AGENT);
        if (t == nblocks - 1) {
            __hip_atomic_store(flag, 1, __ATOMIC_RELEASE,
                               __HIP_MEMORY_SCOPE_AGENT);
        } else {
            while (__hip_atomic_load(flag, __ATOMIC_ACQUIRE,
                                     __HIP_MEMORY_SCOPE_AGENT) == 0)
                __builtin_amdgcn_s_sleep(8);
        }
    }
    __syncthreads();
}

// MFMA GEMM phase over all row tiles. mode 0: bf16 A. mode 1: bf16 A with
// BN(statsIn)+ReLU fused into A load. mode 2: fp32 A (layer-0 input).
__device__ void gemm_phase(char* smem, const void* Ain, const short* Wt,
    const float* bias, short* Cout, float* statsOut,
    const float* statsIn, const float* gamma, const float* beta, int mode)
{
    short (*Bs)[136] = (short(*)[136])smem;          // 34816 B
    float* scale_s = (float*)(smem + 34816);         // 512 B
    float* shift_s = scale_s + 128;                  // 512 B
    const int tid = threadIdx.x;

    if (mode == 1 && tid < 128) {
        const float nInv = 1.0f / (float)N_;
        float mu = statsIn[tid] * nInv;
        float var = statsIn[128 + tid] * nInv - mu * mu;
        float sc = gamma[tid] * rsqrtf(var + BN_EPS);
        scale_s[tid] = sc;
        shift_s[tid] = beta[tid] - mu * sc;
    }

    const int wave = tid >> 6, lane = tid & 63;
    const int m = lane & 15, quad = lane >> 4;

    for (int tile = blockIdx.x; tile < NTILES_; tile += gridDim.x) {
        __syncthreads();                             // protect Bs reuse
        {   // stage W^T
            int r = tid >> 1, half = (tid & 1) << 6;
            const short* g = Wt + r * 128 + half;
            short* d = &Bs[r][half];
#pragma unroll
            for (int i = 0; i < 8; ++i)
                *(short8*)(d + i * 8) = *(const short8*)(g + i * 8);
        }
        __syncthreads();

        const int rowBase = tile * 64;
        int row = rowBase + wave * 16 + m;
        int arow = row < N_ ? row : N_ - 1;

        floatx4 acc[8];
#pragma unroll
        for (int i = 0; i < 8; ++i) acc[i] = (floatx4)0.f;

#pragma unroll
        for (int k0 = 0; k0 < 128; k0 += 32) {
            const int kb = k0 + quad * 8;
            short8 af;
            if (mode == 2) {
                const float* Af = (const float*)Ain + (size_t)arow * 128 + kb;
                float4 x0 = *(const float4*)(Af);
                float4 x1 = *(const float4*)(Af + 4);
                af[0] = f2bf(x0.x); af[1] = f2bf(x0.y); af[2] = f2bf(x0.z); af[3] = f2bf(x0.w);
                af[4] = f2bf(x1.x); af[5] = f2bf(x1.y); af[6] = f2bf(x1.z); af[7] = f2bf(x1.w);
            } else {
                af = *(const short8*)((const short*)Ain + (size_t)arow * 128 + kb);
                if (mode == 1) {
                    float4 sc0 = *(const float4*)&scale_s[kb];
                    float4 sc1 = *(const float4*)&scale_s[kb + 4];
                    float4 sh0 = *(const float4*)&shift_s[kb];
                    float4 sh1 = *(const float4*)&shift_s[kb + 4];
                    af[0] = f2bf(fmaxf(fmaf(bf2f(af[0]), sc0.x, sh0.x), 0.f));
                    af[1] = f2bf(fmaxf(fmaf(bf2f(af[1]), sc0.y, sh0.y), 0.f));
                    af[2] = f2bf(fmaxf(fmaf(bf2f(af[2]), sc0.z, sh0.z), 0.f));
                    af[3] = f2bf(fmaxf(fmaf(bf2f(af[3]), sc0.w, sh0.w), 0.f));
                    af[4] = f2bf(fmaxf(fmaf(bf2f(af[4]), sc1.x, sh1.x), 0.f));
                    af[5] = f2bf(fmaxf(fmaf(bf2f(af[5]), sc1.y, sh1.y), 0.f));
                    af[6] = f2bf(fmaxf(fmaf(bf2f(af[6]), sc1.z, sh1.z), 0.f));
                    af[7] = f2bf(fmaxf(fmaf(bf2f(af[7]), sc1.w, sh1.w), 0.f));
                }
            }
#pragma unroll
            for (int nt = 0; nt < 8; ++nt) {
                short8 bf = *(const short8*)&Bs[nt * 16 + m][kb];
                acc[nt] = __builtin_amdgcn_mfma_f32_16x16x32_bf16(af, bf, acc[nt], 0, 0, 0);
            }
        }

        __syncthreads();
        float (*Cs)[132] = (float(*)[132])smem;      // 33792 B (< 34816, scale_s safe)
#pragma unroll
        for (int nt = 0; nt < 8; ++nt) {
            float b = bias[nt * 16 + m];
#pragma unroll
            for (int r = 0; r < 4; ++r)
                Cs[wave * 16 + quad * 4 + r][nt * 16 + m] = acc[nt][r] + b;
        }
        __syncthreads();

        {
            int trow = tid >> 2;
            int tcg = (tid & 3) << 5;
            int grow = rowBase + trow;
            if (grow < N_) {
                short* dst = Cout + (size_t)grow * 128 + tcg;
#pragma unroll
                for (int i = 0; i < 4; ++i) {
                    short8 o;
#pragma unroll
                    for (int j = 0; j < 8; ++j) o[j] = f2bf(Cs[trow][tcg + i * 8 + j]);
                    *(short8*)(dst + i * 8) = o;
                }
            }
        }
        if (tid < 128) {
            int nvalid = N_ - rowBase;
            if (nvalid > 64) nvalid = 64;
            float S1 = 0.f, S2 = 0.f;
            for (int r = 0; r < nvalid; ++r) {
                float v = Cs[r][tid];
                S1 += v; S2 += v * v;
            }
            atomicAdd(&statsOut[tid], S1);
            atomicAdd(&statsOut[128 + tid], S2);
        }
    }
}

// BN apply + ReLU + segment pool (batch sorted). 2 virtual half-blocks/block.
__device__ void bnpool_phase(const short* Cin, short* hout, const float* stats,
    const float* gamma, const float* beta, const int* batch, float* pooled)
{
    const int tid = threadIdx.x;
    const int c = tid & 127;
    const float nInv = 1.0f / (float)N_;
    float mu = stats[c] * nInv;
    float var = stats[128 + c] * nInv - mu * mu;
    float sc = gamma[c] * rsqrtf(var + BN_EPS);
    float sh = beta[c] - mu * sc;

    int nv = gridDim.x * 2;
    int vblk = blockIdx.x * 2 + (tid >> 7);
    int per = (N_ + nv - 1) / nv;
    int r0 = vblk * per;
    int r1 = min(N_, r0 + per);
    if (r0 < r1) {
        int curg = batch[r0];
        float s = 0.f;
        for (int r = r0; r < r1; ++r) {
            int g = batch[r];
            if (g != curg) {
                atomicAdd(&pooled[(size_t)curg * 128 + c], s);
                s = 0.f;
                curg = g;
            }
            float v = fmaxf(fmaf(bf2f(Cin[(size_t)r * 128 + c]), sc, sh), 0.f);
            hout[(size_t)r * 128 + c] = f2bf(v);
            s += v;
        }
        atomicAdd(&pooled[(size_t)curg * 128 + c], s);
    }
}

// u[i] = (1+eps)*h[i] + sum_{j in N(i)} h[j], one wave per node, 4-wide unroll
__device__ void agg_phase(const short* h, short* u, const int* off,
                          const int* eidx, float se)
{
    const int lane = threadIdx.x & 63;
    const int col = lane * 2;
    const int ngrp = (N_ + 3) / 4;
    for (int grp = blockIdx.x; grp < ngrp; grp += gridDim.x) {
        int node = grp * 4 + (threadIdx.x >> 6);
        if (node < N_) {
            int s0 = off[node];
            int s1 = off[node + 1];
            ushort2 a = *(const ushort2*)(h + (size_t)node * 128 + col);
            float ax = bf2f((short)a.x) * se;
            float ay = bf2f((short)a.y) * se;
            int j = s0;
            for (; j + 3 < s1; j += 4) {
                int n0 = eidx[j], n1 = eidx[j + 1], n2 = eidx[j + 2], n3 = eidx[j + 3];
                ushort2 v0 = *(const ushort2*)(h + (size_t)n0 * 128 + col);
                ushort2 v1 = *(const ushort2*)(h + (size_t)n1 * 128 + col);
                ushort2 v2 = *(const ushort2*)(h + (size_t)n2 * 128 + col);
                ushort2 v3 = *(const ushort2*)(h + (size_t)n3 * 128 + col);
                ax += (bf2f((short)v0.x) + bf2f((short)v1.x))
                    + (bf2f((short)v2.x) + bf2f((short)v3.x));
                ay += (bf2f((short)v0.y) + bf2f((short)v1.y))
                    + (bf2f((short)v2.y) + bf2f((short)v3.y));
            }
            for (; j < s1; ++j) {
                int n0 = eidx[j];
                ushort2 v0 = *(const ushort2*)(h + (size_t)n0 * 128 + col);
                ax += bf2f((short)v0.x);
                ay += bf2f((short)v0.y);
            }
            ushort2 o;
            o.x = (unsigned short)f2bf(ax);
            o.y = (unsigned short)f2bf(ay);
            *(ushort2*)(u + (size_t)node * 128 + col) = o;
        }
    }
}

// out[g*T+t] = sigmoid( sum_l (pooled_l[g]·Wl_l[:,t])/cnt_g + bl_l[t] )
__device__ void out_phase(const float* pooled, const float* cntf,
                          const float* Wl, const float* bl, float* out)
{
    for (int g = blockIdx.x; g < G_; g += gridDim.x) {
        int t = threadIdx.x;
        if (t < T_) {
            float inv = 1.0f / fmaxf(cntf[g], 1.0f);
            float acc = 0.f;
#pragma unroll
            for (int l = 0; l < 4; ++l) {
                float s = 0.f;
                for (int c = 0; c < 128; ++c)
                    s = fmaf(pooled[(size_t)l * (G_ * H_) + g * 128 + c],
                             Wl[(size_t)l * (H_ * T_) + c * T_ + t], s);
                acc += s * inv + bl[l * T_ + t];
            }
            out[g * T_ + t] = 1.0f / (1.0f + expf(-acc));
        }
    }
}

__global__ __launch_bounds__(256, 3) void gin_net(GinParams p)
{
    __shared__ __align__(16) char smem[36864];
    int* barr = p.barr;
    const int nb = gridDim.x;

    // layer 0
    gemm_phase(smem, p.x, p.Wt, p.ba, p.R, p.stats, nullptr, nullptr, nullptr, 2);
    gbar(barr, 0, nb);
    gemm_phase(smem, p.R, p.Wt + 4 * 16384, p.bb, p.Q, p.stats + 256,
               p.stats, p.ga, p.bea, 1);
    gbar(barr, 1, nb);
    bnpool_phase(p.Q, p.P, p.stats + 256, p.gb, p.beb, p.batch, p.pooled);
    gbar(barr, 2, nb);

    int bi = 3;
    for (int l = 1; l < 4; ++l) {
        float se = 1.0f + p.eps[l - 1];
        agg_phase(p.P, p.Q, p.off, p.eidx, se);
        gbar(barr, bi++, nb);
        gemm_phase(smem, p.Q, p.Wt + (size_t)l * 16384, p.ba + l * 128, p.R,
                   p.stats + (size_t)(2 * l) * 256, nullptr, nullptr, nullptr, 0);
        gbar(barr, bi++, nb);
        gemm_phase(smem, p.R, p.Wt + (size_t)(4 + l) * 16384, p.bb + l * 128, p.Q,
                   p.stats + (size_t)(2 * l + 1) * 256,
                   p.stats + (size_t)(2 * l) * 256, p.ga + l * 128, p.bea + l * 128, 1);
        gbar(barr, bi++, nb);
        bnpool_phase(p.Q, p.P, p.stats + (size_t)(2 * l + 1) * 256,
                     p.gb + l * 128, p.beb + l * 128, p.batch,
                     p.pooled + (size_t)l * (G_ * H_));
        gbar(barr, bi++, nb);
    }
    out_phase(p.pooled, p.cntf, p.Wl, p.bl, p.out);
}

// ---------------------------------------------------------------------------
extern "C" void kernel_launch(void* const* d_in, const int* in_sizes, int n_in,
                              void* d_out, int out_size, void* d_ws, size_t ws_size,
                              hipStream_t stream)
{
    const float* x    = (const float*)d_in[0];
    const int*   ei   = (const int*)d_in[1];
    const int*   batch= (const int*)d_in[2];
    const float* Wa   = (const float*)d_in[3];
    const float* ba   = (const float*)d_in[4];
    const float* ga   = (const float*)d_in[5];
    const float* bea  = (const float*)d_in[6];
    const float* Wb   = (const float*)d_in[7];
    const float* bb   = (const float*)d_in[8];
    const float* gb   = (const float*)d_in[9];
    const float* beb  = (const float*)d_in[10];
    const float* Wl   = (const float*)d_in[11];
    const float* bl   = (const float*)d_in[12];
    const float* eps  = (const float*)d_in[13];
    float* out = (float*)d_out;

    const size_t NH = (size_t)N_ * H_;
    // workspace layout
    short* P   = (short*)d_ws;                 // N x H bf16 (h)
    short* Q   = P + NH;                       // N x H bf16 (u / D)
    short* R   = Q + NH;                       // N x H bf16 (C)
    short* Wt  = R + NH;                       // 8 x 128 x 128 bf16
    float* stats  = (float*)(Wt + 8 * 16384);  // 8 x 256          [zeroed]
    float* pooled = stats + 8 * 256;           // 4 x G x 128      [zeroed]
    float* cntf   = pooled + 4 * (size_t)G_ * H_; // G             [zeroed]
    int*   barr   = (int*)(cntf + G_);         // 64 ints          [zeroed]
    int*   X      = barr + 64;                 // SCANN_           [zeroed]
    int*   Y      = X + SCANN_;                // SCANN_
    int*   bsum   = Y + SCANN_;                // 256
    int2*  ebuf   = (int2*)(bsum + 256);       // E
    int*   eidx   = (int*)(ebuf + E_);         // E

    const size_t zbytes = (size_t)(8 * 256 + 4 * G_ * H_ + G_ + 64 + SCANN_) * 4;
    hipMemsetAsync(stats, 0, zbytes, stream);

    const int* esrc = ei;
    const int* edst = ei + E_;

    prep<<<NBLK_, 256, 0, stream>>>(Wa, Wb, Wt, batch, cntf, edst, X);
    scan_all<<<SCANB_, 256, 0, stream>>>(X, Y, bsum, barr);
    scatter_csr<<<NB_, 256, 0, stream>>>(esrc, edst, Y, ebuf, eidx, barr);

    GinParams prm;
    prm.x = x; prm.batch = batch; prm.Wt = Wt;
    prm.ba = ba; prm.ga = ga; prm.bea = bea;
    prm.bb = bb; prm.gb = gb; prm.beb = beb;
    prm.Wl = Wl; prm.bl = bl; prm.eps = eps;
    prm.off = Y; prm.eidx = eidx;
    prm.P = P; prm.Q = Q; prm.R = R;
    prm.stats = stats; prm.pooled = pooled; prm.cntf = cntf;
    prm.barr = barr; prm.out = out;

    gin_net<<<GRID_, 256, 0, stream>>>(prm);
}

// Round 5
// 1025.961 us; speedup vs baseline: 4.0275x; 4.0275x over previous
//
#include <hip/hip_runtime.h>
#include <hip/hip_bf16.h>

#define N_      100000
#define E_      1600000
#define G_      512
#define H_      128
#define T_      10
#define BN_EPS  1e-5f

#define NB_     782        // dst buckets of 128 nodes: ceil(100000/128)
#define NBLK_   200        // edge-chunk blocks (8000 edges each)
#define ECHUNK_ 8000
#define SCANN_  (NB_ * NBLK_)          // 156400 bucket-histogram entries
#define SCANB_  ((SCANN_ + 1023) / 1024)  // 153 scan blocks

typedef __attribute__((ext_vector_type(8))) short short8;
typedef __attribute__((ext_vector_type(4))) float floatx4;

__device__ __forceinline__ float bf2f(short s) {
    return __uint_as_float(((unsigned int)(unsigned short)s) << 16);
}
__device__ __forceinline__ short f2bf(float f) {
    unsigned int u = __float_as_uint(f);
    u += 0x7fffu + ((u >> 16) & 1u);          // round-to-nearest-even
    return (short)(u >> 16);
}

// ---------------------------------------------------------------------------
// prep: convert weights to bf16 W^T + per-graph node counts + per-(bucket,
// block) edge histogram BH[b*NBLK_+blk].  grid = NBLK_ x 256.
// ---------------------------------------------------------------------------
__global__ __launch_bounds__(256) void prep(
    const float* __restrict__ Wa, const float* __restrict__ Wb,
    short* __restrict__ Wt, const int* __restrict__ batch,
    float* __restrict__ cntf, const int* __restrict__ edst,
    int* __restrict__ BH)
{
    __shared__ int hist[NB_];
    const int t = threadIdx.x, blk = blockIdx.x;
    for (int i = t; i < NB_; i += 256) hist[i] = 0;
    __syncthreads();

    const int gtid = blk * 256 + t;
    // convert W (8 mats of 128x128): Wt[mat][n*128+k] = bf16(W[mat][k*128+n])
    for (int i = gtid; i < 8 * 16384; i += NBLK_ * 256) {
        int mat = i >> 14;
        int rem = i & 16383;
        int k = rem >> 7;
        int n = rem & 127;
        const float* W = (mat < 4) ? (Wa + (size_t)mat * 16384)
                                   : (Wb + (size_t)(mat - 4) * 16384);
        Wt[(size_t)mat * 16384 + n * 128 + k] = f2bf(W[k * 128 + n]);
    }
    // per-graph node counts
    for (int i = gtid; i < N_; i += NBLK_ * 256)
        atomicAdd(&cntf[batch[i]], 1.0f);
    // bucket histogram for this block's edge chunk (LDS atomics only)
    const int base = blk * ECHUNK_;
    for (int i = base + t; i < base + ECHUNK_; i += 256)
        atomicAdd(&hist[edst[i] >> 7], 1);
    __syncthreads();
    for (int b = t; b < NB_; b += 256)
        BH[b * NBLK_ + blk] = hist[b];
}

// ---------------------------------------------------------------------------
// Exclusive scan of BH[SCANN_] -> BHs (3 small kernels)
// ---------------------------------------------------------------------------
__global__ __launch_bounds__(256) void scan1(const int* __restrict__ X,
                                             int* __restrict__ Y,
                                             int* __restrict__ bsum, int n)
{
    __shared__ int sd[256];
    int t = threadIdx.x;
    int base = blockIdx.x * 1024 + t * 4;
    int c0 = (base + 0 < n) ? X[base + 0] : 0;
    int c1 = (base + 1 < n) ? X[base + 1] : 0;
    int c2 = (base + 2 < n) ? X[base + 2] : 0;
    int c3 = (base + 3 < n) ? X[base + 3] : 0;
    int s = c0 + c1 + c2 + c3;
    sd[t] = s;
    __syncthreads();
    for (int d = 1; d < 256; d <<= 1) {
        int v = (t >= d) ? sd[t - d] : 0;
        __syncthreads();
        sd[t] += v;
        __syncthreads();
    }
    int p = sd[t] - s;
    if (base + 0 < n) Y[base + 0] = p;
    if (base + 1 < n) Y[base + 1] = p + c0;
    if (base + 2 < n) Y[base + 2] = p + c0 + c1;
    if (base + 3 < n) Y[base + 3] = p + c0 + c1 + c2;
    if (t == 255) bsum[blockIdx.x] = sd[255];
}

__global__ __launch_bounds__(256) void scan2(int* __restrict__ bsum, int nb)
{
    __shared__ int sd[256];
    int t = threadIdx.x;
    int v0 = (t < nb) ? bsum[t] : 0;
    sd[t] = v0;
    __syncthreads();
    for (int d = 1; d < 256; d <<= 1) {
        int v = (t >= d) ? sd[t - d] : 0;
        __syncthreads();
        sd[t] += v;
        __syncthreads();
    }
    if (t < nb) bsum[t] = sd[t] - v0;
}

__global__ __launch_bounds__(256) void scan3(int* __restrict__ Y,
                                             const int* __restrict__ bsum, int n)
{
    int t = threadIdx.x;
    int base = blockIdx.x * 1024 + t * 4;
    int add = bsum[blockIdx.x];
#pragma unroll
    for (int i = 0; i < 4; ++i)
        if (base + i < n) Y[base + i] += add;
}

// ---------------------------------------------------------------------------
// scatter_ebuf: each chunk block writes its edges into bucket-grouped ebuf.
// Per-(bucket,block) regions are exclusive & contiguous -> ~no write amp.
// ---------------------------------------------------------------------------
__global__ __launch_bounds__(256) void scatter_ebuf(
    const int* __restrict__ esrc, const int* __restrict__ edst,
    const int* __restrict__ BHs, int2* __restrict__ ebuf)
{
    __shared__ int sbuf[NB_];
    const int t = threadIdx.x, blk = blockIdx.x;
    for (int b = t; b < NB_; b += 256)
        sbuf[b] = BHs[b * NBLK_ + blk];
    __syncthreads();
    const int base = blk * ECHUNK_;
    for (int i = base + t; i < base + ECHUNK_; i += 256) {
        int s = esrc[i], d = edst[i];
        int pos = atomicAdd(&sbuf[d >> 7], 1);
        ebuf[pos] = make_int2(s, d);
    }
}

// ---------------------------------------------------------------------------
// fill_buckets: bucket b (128 nodes) -> exact CSR eidx + off[], all writes
// confined to this block's contiguous regions.  Also derives per-node offsets
// locally (no global per-node histogram needed).
// ---------------------------------------------------------------------------
__global__ __launch_bounds__(256) void fill_buckets(
    const int2* __restrict__ ebuf, const int* __restrict__ BHs,
    int* __restrict__ eidx, int* __restrict__ off)
{
    __shared__ int cnt[128];
    __shared__ int sc[256];
    const int b = blockIdx.x, t = threadIdx.x;
    const int bstart = BHs[b * NBLK_];
    const int bend = (b == NB_ - 1) ? E_ : BHs[(b + 1) * NBLK_];

    if (t < 128) cnt[t] = 0;
    __syncthreads();
    for (int i = bstart + t; i < bend; i += 256)
        atomicAdd(&cnt[ebuf[i].y & 127], 1);
    __syncthreads();
    int v = (t < 128) ? cnt[t] : 0;
    sc[t] = v;
    __syncthreads();
    for (int d = 1; d < 128; d <<= 1) {
        int u = (t >= d) ? sc[t - d] : 0;
        __syncthreads();
        sc[t] += u;
        __syncthreads();
    }
    if (t < 128) {
        int node = (b << 7) + t;
        int pfx = sc[t] - v;
        if (node <= N_) off[node] = bstart + pfx;
        cnt[t] = bstart + pfx;                    // cursor
    }
    __syncthreads();
    for (int i = bstart + t; i < bend; i += 256) {
        int2 e = ebuf[i];
        int pos = atomicAdd(&cnt[e.y & 127], 1);
        eidx[pos] = e.x;
    }
}

// ---------------------------------------------------------------------------
// MFMA GEMM: C[nrows x 128](bf16) = act(A) @ W + bias, fused BN-stats output.
// mode 0: A bf16, plain.  mode 1: A bf16, BN(statsIn)+ReLU fused into A-load.
// mode 2: A fp32, plain (layer-0 x input).
// ---------------------------------------------------------------------------
__global__ __launch_bounds__(256) void gemm_mfma(
    const void* __restrict__ Ain, const short* __restrict__ Wt,
    const float* __restrict__ bias, short* __restrict__ Cout,
    float* __restrict__ statsOut,
    const float* __restrict__ statsIn, const float* __restrict__ gamma,
    const float* __restrict__ beta, int mode, int nrows)
{
    __shared__ __align__(16) short Bs[128][136];
    __shared__ float scale_s[128];
    __shared__ float shift_s[128];

    const int tid = threadIdx.x;

    {   // stage W^T
        int r = tid >> 1;
        int half = (tid & 1) << 6;
        const short* g = Wt + r * 128 + half;
        short* d = &Bs[r][half];
#pragma unroll
        for (int i = 0; i < 8; ++i)
            *(short8*)(d + i * 8) = *(const short8*)(g + i * 8);
    }
    if (mode == 1 && tid < 128) {
        const float nInv = 1.0f / (float)N_;
        float mu = statsIn[tid] * nInv;
        float var = statsIn[128 + tid] * nInv - mu * mu;
        float sc = gamma[tid] * rsqrtf(var + BN_EPS);
        scale_s[tid] = sc;
        shift_s[tid] = beta[tid] - mu * sc;
    }
    __syncthreads();

    const int wave = tid >> 6;
    const int lane = tid & 63;
    const int m = lane & 15;
    const int quad = lane >> 4;
    const int rowBase = blockIdx.x * 64;
    int row = rowBase + wave * 16 + m;
    int arow = row < nrows ? row : nrows - 1;

    floatx4 acc[8];
#pragma unroll
    for (int i = 0; i < 8; ++i) acc[i] = (floatx4)0.f;

#pragma unroll
    for (int k0 = 0; k0 < 128; k0 += 32) {
        const int kb = k0 + quad * 8;
        short8 af;
        if (mode == 2) {
            const float* Af = (const float*)Ain + (size_t)arow * 128 + kb;
            float4 x0 = *(const float4*)(Af);
            float4 x1 = *(const float4*)(Af + 4);
            af[0] = f2bf(x0.x); af[1] = f2bf(x0.y); af[2] = f2bf(x0.z); af[3] = f2bf(x0.w);
            af[4] = f2bf(x1.x); af[5] = f2bf(x1.y); af[6] = f2bf(x1.z); af[7] = f2bf(x1.w);
        } else {
            af = *(const short8*)((const short*)Ain + (size_t)arow * 128 + kb);
            if (mode == 1) {
                float4 sc0 = *(const float4*)&scale_s[kb];
                float4 sc1 = *(const float4*)&scale_s[kb + 4];
                float4 sh0 = *(const float4*)&shift_s[kb];
                float4 sh1 = *(const float4*)&shift_s[kb + 4];
                af[0] = f2bf(fmaxf(fmaf(bf2f(af[0]), sc0.x, sh0.x), 0.f));
                af[1] = f2bf(fmaxf(fmaf(bf2f(af[1]), sc0.y, sh0.y), 0.f));
                af[2] = f2bf(fmaxf(fmaf(bf2f(af[2]), sc0.z, sh0.z), 0.f));
                af[3] = f2bf(fmaxf(fmaf(bf2f(af[3]), sc0.w, sh0.w), 0.f));
                af[4] = f2bf(fmaxf(fmaf(bf2f(af[4]), sc1.x, sh1.x), 0.f));
                af[5] = f2bf(fmaxf(fmaf(bf2f(af[5]), sc1.y, sh1.y), 0.f));
                af[6] = f2bf(fmaxf(fmaf(bf2f(af[6]), sc1.z, sh1.z), 0.f));
                af[7] = f2bf(fmaxf(fmaf(bf2f(af[7]), sc1.w, sh1.w), 0.f));
            }
        }
#pragma unroll
        for (int nt = 0; nt < 8; ++nt) {
            short8 bf = *(const short8*)&Bs[nt * 16 + m][kb];
            acc[nt] = __builtin_amdgcn_mfma_f32_16x16x32_bf16(af, bf, acc[nt], 0, 0, 0);
        }
    }

    __syncthreads();
    float (*Cs)[132] = (float(*)[132])&Bs[0][0];
#pragma unroll
    for (int nt = 0; nt < 8; ++nt) {
        float b = bias[nt * 16 + m];
#pragma unroll
        for (int r = 0; r < 4; ++r)
            Cs[wave * 16 + quad * 4 + r][nt * 16 + m] = acc[nt][r] + b;
    }
    __syncthreads();

    {
        int trow = tid >> 2;
        int tcg = (tid & 3) << 5;
        int grow = rowBase + trow;
        if (grow < nrows) {
            short* dst = Cout + (size_t)grow * 128 + tcg;
#pragma unroll
            for (int i = 0; i < 4; ++i) {
                short8 o;
#pragma unroll
                for (int j = 0; j < 8; ++j) o[j] = f2bf(Cs[trow][tcg + i * 8 + j]);
                *(short8*)(dst + i * 8) = o;
            }
        }
    }
    if (tid < 128) {
        int nvalid = nrows - rowBase;
        if (nvalid > 64) nvalid = 64;
        float S1 = 0.f, S2 = 0.f;
        for (int r = 0; r < nvalid; ++r) {
            float v = Cs[r][tid];
            S1 += v; S2 += v * v;
        }
        atomicAdd(&statsOut[tid], S1);
        atomicAdd(&statsOut[128 + tid], S2);
    }
}

// ---------------------------------------------------------------------------
// BN apply + ReLU + segment pool, streaming. Block=128 thr (thread = column).
// ---------------------------------------------------------------------------
__global__ __launch_bounds__(128) void bn_relu_pool(
    const short* __restrict__ Cin, short* __restrict__ hout,
    const float* __restrict__ stats, const float* __restrict__ gamma,
    const float* __restrict__ beta, const int* __restrict__ batch,
    float* __restrict__ pooled, int n)
{
    int c = threadIdx.x;
    const float nInv = 1.0f / (float)N_;
    float mu = stats[c] * nInv;
    float var = stats[128 + c] * nInv - mu * mu;
    float sc = gamma[c] * rsqrtf(var + BN_EPS);
    float sh = beta[c] - mu * sc;

    int per = (n + gridDim.x - 1) / gridDim.x;
    int r0 = blockIdx.x * per;
    int r1 = min(n, r0 + per);
    if (r0 >= r1) return;
    int curg = batch[r0];
    float s = 0.f;
    for (int r = r0; r < r1; ++r) {
        int g = batch[r];
        if (g != curg) {
            atomicAdd(&pooled[(size_t)curg * 128 + c], s);
            s = 0.f;
            curg = g;
        }
        float v = fmaxf(fmaf(bf2f(Cin[(size_t)r * 128 + c]), sc, sh), 0.f);
        hout[(size_t)r * 128 + c] = f2bf(v);
        s += v;
    }
    atomicAdd(&pooled[(size_t)curg * 128 + c], s);
}

// ---------------------------------------------------------------------------
// GIN aggregation (bf16): u[i] = (1+eps)*h[i] + sum_{j in N(i)} h[j]
// One wave per node; lane = 2 cols (4 B) -> 256 B coalesced per neighbor.
// ---------------------------------------------------------------------------
__global__ __launch_bounds__(256) void aggregate(
    const short* __restrict__ h, short* __restrict__ u,
    const int* __restrict__ off, const int* __restrict__ eidx,
    const float* __restrict__ eps, int li)
{
    int node = blockIdx.x * 4 + (threadIdx.x >> 6);
    if (node >= N_) return;
    int lane = threadIdx.x & 63;
    int col = lane * 2;

    int s0 = off[node];
    int s1 = off[node + 1];
    float se = 1.0f + eps[li];

    ushort2 a = *(const ushort2*)(h + (size_t)node * 128 + col);
    float ax = bf2f((short)a.x) * se;
    float ay = bf2f((short)a.y) * se;

    int j = s0;
    for (; j + 3 < s1; j += 4) {
        int n0 = eidx[j], n1 = eidx[j + 1], n2 = eidx[j + 2], n3 = eidx[j + 3];
        ushort2 v0 = *(const ushort2*)(h + (size_t)n0 * 128 + col);
        ushort2 v1 = *(const ushort2*)(h + (size_t)n1 * 128 + col);
        ushort2 v2 = *(const ushort2*)(h + (size_t)n2 * 128 + col);
        ushort2 v3 = *(const ushort2*)(h + (size_t)n3 * 128 + col);
        ax += (bf2f((short)v0.x) + bf2f((short)v1.x))
            + (bf2f((short)v2.x) + bf2f((short)v3.x));
        ay += (bf2f((short)v0.y) + bf2f((short)v1.y))
            + (bf2f((short)v2.y) + bf2f((short)v3.y));
    }
    for (; j < s1; ++j) {
        int n0 = eidx[j];
        ushort2 v0 = *(const ushort2*)(h + (size_t)n0 * 128 + col);
        ax += bf2f((short)v0.x);
        ay += bf2f((short)v0.y);
    }
    ushort2 o;
    o.x = (unsigned short)f2bf(ax);
    o.y = (unsigned short)f2bf(ay);
    *(ushort2*)(u + (size_t)node * 128 + col) = o;
}

// ---------------------------------------------------------------------------
// out_final: out[g*T+t] = sigmoid(sum_l pooled_l[g]·Wl_l[:,t]/cnt_g + bl_l[t])
// ---------------------------------------------------------------------------
__global__ void out_final(const float* __restrict__ pooled,
                          const float* __restrict__ cntf,
                          const float* __restrict__ Wl,
                          const float* __restrict__ bl, float* __restrict__ out)
{
    int g = blockIdx.x;
    int t = threadIdx.x;
    if (t >= T_) return;
    float inv = 1.0f / fmaxf(cntf[g], 1.0f);
    float acc = 0.f;
#pragma unroll
    for (int l = 0; l < 4; ++l) {
        float s = 0.f;
        for (int c = 0; c < 128; ++c)
            s = fmaf(pooled[(size_t)l * (G_ * H_) + g * 128 + c],
                     Wl[(size_t)l * (H_ * T_) + c * T_ + t], s);
        acc += s * inv + bl[l * T_ + t];
    }
    out[g * T_ + t] = 1.0f / (1.0f + expf(-acc));
}

// ---------------------------------------------------------------------------
extern "C" void kernel_launch(void* const* d_in, const int* in_sizes, int n_in,
                              void* d_out, int out_size, void* d_ws, size_t ws_size,
                              hipStream_t stream)
{
    const float* x    = (const float*)d_in[0];
    const int*   ei   = (const int*)d_in[1];
    const int*   batch= (const int*)d_in[2];
    const float* Wa   = (const float*)d_in[3];
    const float* ba   = (const float*)d_in[4];
    const float* ga   = (const float*)d_in[5];
    const float* bea  = (const float*)d_in[6];
    const float* Wb   = (const float*)d_in[7];
    const float* bb   = (const float*)d_in[8];
    const float* gb   = (const float*)d_in[9];
    const float* beb  = (const float*)d_in[10];
    const float* Wl   = (const float*)d_in[11];
    const float* bl   = (const float*)d_in[12];
    const float* eps  = (const float*)d_in[13];
    float* out = (float*)d_out;

    const size_t NH = (size_t)N_ * H_;
    // workspace layout
    short* P   = (short*)d_ws;                 // N x H bf16 (h)
    short* Q   = P + NH;                       // N x H bf16
    short* R   = Q + NH;                       // N x H bf16
    short* Wt  = R + NH;                       // 8 x 128 x 128 bf16
    float* stats  = (float*)(Wt + 8 * 16384);  // 8 x 256          [zeroed]
    float* pooled = stats + 8 * 256;           // 4 x G x 128      [zeroed]
    float* cntf   = pooled + 4 * (size_t)G_ * H_; // G             [zeroed]
    int*   BH     = (int*)(cntf + G_);         // SCANN_           [zeroed]
    int*   BHs    = BH + SCANN_;               // SCANN_
    int*   bsum   = BHs + SCANN_;              // 256
    int*   off    = bsum + 256;                // 100352 (>= N_+1)
    int2*  ebuf   = (int2*)(off + 100352);     // E
    int*   eidx   = (int*)(ebuf + E_);         // E

    const size_t zbytes = (size_t)(8 * 256 + 4 * G_ * H_ + G_ + SCANN_) * 4;
    hipMemsetAsync(stats, 0, zbytes, stream);

    const int* esrc = ei;
    const int* edst = ei + E_;

    // ---- CSR build (bucket counting sort, no write amplification) ----
    prep<<<NBLK_, 256, 0, stream>>>(Wa, Wb, Wt, batch, cntf, edst, BH);
    scan1<<<SCANB_, 256, 0, stream>>>(BH, BHs, bsum, SCANN_);
    scan2<<<1, 256, 0, stream>>>(bsum, SCANB_);
    scan3<<<SCANB_, 256, 0, stream>>>(BHs, bsum, SCANN_);
    scatter_ebuf<<<NBLK_, 256, 0, stream>>>(esrc, edst, BHs, ebuf);
    fill_buckets<<<NB_, 256, 0, stream>>>(ebuf, BHs, eidx, off);

    const int gemmGrid = (N_ + 63) / 64;
    const int aggGrid = (N_ + 3) / 4;

    // ---- layer 0 ----
    gemm_mfma<<<gemmGrid, 256, 0, stream>>>(x, Wt, ba, R, stats,
                                            nullptr, nullptr, nullptr, 2, N_);
    gemm_mfma<<<gemmGrid, 256, 0, stream>>>(R, Wt + 4 * 16384, bb, Q, stats + 256,
                                            stats, ga, bea, 1, N_);
    bn_relu_pool<<<1024, 128, 0, stream>>>(Q, P, stats + 256, gb, beb, batch, pooled, N_);

    for (int l = 1; l < 4; ++l) {
        float* stA = stats + (size_t)(2 * l) * 256;
        float* stB = stats + (size_t)(2 * l + 1) * 256;
        aggregate<<<aggGrid, 256, 0, stream>>>(P, Q, off, eidx, eps, l - 1);
        gemm_mfma<<<gemmGrid, 256, 0, stream>>>(Q, Wt + (size_t)l * 16384,
                                                ba + l * H_, R, stA,
                                                nullptr, nullptr, nullptr, 0, N_);
        gemm_mfma<<<gemmGrid, 256, 0, stream>>>(R, Wt + (size_t)(4 + l) * 16384,
                                                bb + l * H_, Q, stB,
                                                stA, ga + l * H_, bea + l * H_, 1, N_);
        bn_relu_pool<<<1024, 128, 0, stream>>>(Q, P, stB, gb + l * H_, beb + l * H_,
                                               batch, pooled + (size_t)l * G_ * H_, N_);
    }

    out_final<<<G_, 64, 0, stream>>>(pooled, cntf, Wl, bl, out);
}

// Round 6
// 796.995 us; speedup vs baseline: 5.1845x; 1.2873x over previous
//
#include <hip/hip_runtime.h>
#include <hip/hip_bf16.h>

#define N_      100000
#define E_      1600000
#define G_      512
#define H_      128
#define T_      10
#define BN_EPS  1e-5f

#define NB_     782        // dst buckets of 128 nodes: ceil(100000/128)
#define NBLK_   256        // edge-chunk blocks (6250 edges each)
#define ECHUNK_ 6250
#define SCANN_  (NB_ * NBLK_)             // 200192 bucket-histogram entries
#define SCANB_  ((SCANN_ + 1023) / 1024)  // 196 scan blocks (<=256 for scan2)

typedef __attribute__((ext_vector_type(8))) short short8;
typedef __attribute__((ext_vector_type(4))) float floatx4;

__device__ __forceinline__ float bf2f(short s) {
    return __uint_as_float(((unsigned int)(unsigned short)s) << 16);
}
__device__ __forceinline__ short f2bf(float f) {
    unsigned int u = __float_as_uint(f);
    u += 0x7fffu + ((u >> 16) & 1u);          // round-to-nearest-even
    return (short)(u >> 16);
}

// ---------------------------------------------------------------------------
// convert_W: Wt[mat][n*128+k] = bf16(W[mat][k*128+n]); mats 0-3 Wa, 4-7 Wb.
// ---------------------------------------------------------------------------
__global__ __launch_bounds__(256) void convert_W(
    const float* __restrict__ Wa, const float* __restrict__ Wb,
    short* __restrict__ Wt)
{
    int i = blockIdx.x * 256 + threadIdx.x;      // 131072 total
    if (i >= 8 * 16384) return;
    int mat = i >> 14;
    int rem = i & 16383;
    int n = rem >> 7;
    int k = rem & 127;                            // k contiguous -> write coalesced
    const float* W = (mat < 4) ? (Wa + (size_t)mat * 16384)
                               : (Wb + (size_t)(mat - 4) * 16384);
    Wt[(size_t)mat * 16384 + n * 128 + k] = f2bf(W[k * 128 + n]);
}

// ---------------------------------------------------------------------------
// count_graphs: batch is sorted -> per-graph node count via binary search.
// ---------------------------------------------------------------------------
__global__ void count_graphs(const int* __restrict__ batch, float* __restrict__ cntf)
{
    int g = blockIdx.x * blockDim.x + threadIdx.x;
    if (g >= G_) return;
    int lo = 0, hi = N_;
    while (lo < hi) { int mid = (lo + hi) >> 1; if (batch[mid] < g) lo = mid + 1; else hi = mid; }
    int lb0 = lo;
    lo = 0; hi = N_;
    while (lo < hi) { int mid = (lo + hi) >> 1; if (batch[mid] < g + 1) lo = mid + 1; else hi = mid; }
    cntf[g] = (float)(lo - lb0);
}

// ---------------------------------------------------------------------------
// edge_hist: per-(bucket, chunk-block) histogram BH[b*NBLK_+blk] (LDS atomics).
// ---------------------------------------------------------------------------
__global__ __launch_bounds__(256) void edge_hist(const int* __restrict__ edst,
                                                 int* __restrict__ BH)
{
    __shared__ int hist[NB_];
    const int t = threadIdx.x, blk = blockIdx.x;
    for (int i = t; i < NB_; i += 256) hist[i] = 0;
    __syncthreads();
    const int base = blk * ECHUNK_;
    for (int i = base + t; i < base + ECHUNK_; i += 256)
        atomicAdd(&hist[edst[i] >> 7], 1);
    __syncthreads();
    for (int b = t; b < NB_; b += 256)
        BH[b * NBLK_ + blk] = hist[b];
}

// ---------------------------------------------------------------------------
// Exclusive scan of BH[SCANN_] -> BHs (3 small kernels)
// ---------------------------------------------------------------------------
__global__ __launch_bounds__(256) void scan1(const int* __restrict__ X,
                                             int* __restrict__ Y,
                                             int* __restrict__ bsum, int n)
{
    __shared__ int sd[256];
    int t = threadIdx.x;
    int base = blockIdx.x * 1024 + t * 4;
    int c0 = (base + 0 < n) ? X[base + 0] : 0;
    int c1 = (base + 1 < n) ? X[base + 1] : 0;
    int c2 = (base + 2 < n) ? X[base + 2] : 0;
    int c3 = (base + 3 < n) ? X[base + 3] : 0;
    int s = c0 + c1 + c2 + c3;
    sd[t] = s;
    __syncthreads();
    for (int d = 1; d < 256; d <<= 1) {
        int v = (t >= d) ? sd[t - d] : 0;
        __syncthreads();
        sd[t] += v;
        __syncthreads();
    }
    int p = sd[t] - s;
    if (base + 0 < n) Y[base + 0] = p;
    if (base + 1 < n) Y[base + 1] = p + c0;
    if (base + 2 < n) Y[base + 2] = p + c0 + c1;
    if (base + 3 < n) Y[base + 3] = p + c0 + c1 + c2;
    if (t == 255) bsum[blockIdx.x] = sd[255];
}

__global__ __launch_bounds__(256) void scan2(int* __restrict__ bsum, int nb)
{
    __shared__ int sd[256];
    int t = threadIdx.x;
    int v0 = (t < nb) ? bsum[t] : 0;
    sd[t] = v0;
    __syncthreads();
    for (int d = 1; d < 256; d <<= 1) {
        int v = (t >= d) ? sd[t - d] : 0;
        __syncthreads();
        sd[t] += v;
        __syncthreads();
    }
    if (t < nb) bsum[t] = sd[t] - v0;
}

__global__ __launch_bounds__(256) void scan3(int* __restrict__ Y,
                                             const int* __restrict__ bsum, int n)
{
    int t = threadIdx.x;
    int base = blockIdx.x * 1024 + t * 4;
    int add = bsum[blockIdx.x];
#pragma unroll
    for (int i = 0; i < 4; ++i)
        if (base + i < n) Y[base + i] += add;
}

// ---------------------------------------------------------------------------
// scatter_ebuf: chunk block -> bucket-grouped ebuf (exclusive regions).
// ---------------------------------------------------------------------------
__global__ __launch_bounds__(256) void scatter_ebuf(
    const int* __restrict__ esrc, const int* __restrict__ edst,
    const int* __restrict__ BHs, int2* __restrict__ ebuf)
{
    __shared__ int sbuf[NB_];
    const int t = threadIdx.x, blk = blockIdx.x;
    for (int b = t; b < NB_; b += 256)
        sbuf[b] = BHs[b * NBLK_ + blk];
    __syncthreads();
    const int base = blk * ECHUNK_;
    for (int i = base + t; i < base + ECHUNK_; i += 256) {
        int s = esrc[i], d = edst[i];
        int pos = atomicAdd(&sbuf[d >> 7], 1);
        ebuf[pos] = make_int2(s, d);
    }
}

// ---------------------------------------------------------------------------
// fill_buckets: bucket b -> exact CSR eidx + off[]; writes confined to the
// block's contiguous region.
// ---------------------------------------------------------------------------
__global__ __launch_bounds__(256) void fill_buckets(
    const int2* __restrict__ ebuf, const int* __restrict__ BHs,
    int* __restrict__ eidx, int* __restrict__ off)
{
    __shared__ int cnt[128];
    __shared__ int sc[256];
    const int b = blockIdx.x, t = threadIdx.x;
    const int bstart = BHs[b * NBLK_];
    const int bend = (b == NB_ - 1) ? E_ : BHs[(b + 1) * NBLK_];

    if (t < 128) cnt[t] = 0;
    __syncthreads();
    for (int i = bstart + t; i < bend; i += 256)
        atomicAdd(&cnt[ebuf[i].y & 127], 1);
    __syncthreads();
    int v = (t < 128) ? cnt[t] : 0;
    sc[t] = v;
    __syncthreads();
    for (int d = 1; d < 128; d <<= 1) {
        int u = (t >= d) ? sc[t - d] : 0;
        __syncthreads();
        sc[t] += u;
        __syncthreads();
    }
    if (t < 128) {
        int node = (b << 7) + t;
        int pfx = sc[t] - v;
        if (node <= N_) off[node] = bstart + pfx;
        cnt[t] = bstart + pfx;                    // cursor
    }
    __syncthreads();
    for (int i = bstart + t; i < bend; i += 256) {
        int2 e = ebuf[i];
        int pos = atomicAdd(&cnt[e.y & 127], 1);
        eidx[pos] = e.x;
    }
}

// ---------------------------------------------------------------------------
// MFMA GEMM: C[nrows x 128](bf16) = act(A) @ W + bias, fused BN-stats output.
// mode 0: A bf16. mode 1: A bf16, BN(statsIn)+ReLU fused into A-load.
// mode 2: A fp32 (layer-0 x). Tile: 128 rows x 128 cols, 4 waves, 2 m-subtiles
// per wave, two-half LDS epilogue.
// ---------------------------------------------------------------------------
__global__ __launch_bounds__(256) void gemm_mfma(
    const void* __restrict__ Ain, const short* __restrict__ Wt,
    const float* __restrict__ bias, short* __restrict__ Cout,
    float* __restrict__ statsOut,
    const float* __restrict__ statsIn, const float* __restrict__ gamma,
    const float* __restrict__ beta, int mode, int nrows)
{
    __shared__ __align__(16) short Bs[128][136];
    __shared__ float scale_s[128];
    __shared__ float shift_s[128];

    const int tid = threadIdx.x;

    {   // stage W^T
        int r = tid >> 1;
        int half = (tid & 1) << 6;
        const short* g = Wt + r * 128 + half;
        short* d = &Bs[r][half];
#pragma unroll
        for (int i = 0; i < 8; ++i)
            *(short8*)(d + i * 8) = *(const short8*)(g + i * 8);
    }
    if (mode == 1 && tid < 128) {
        const float nInv = 1.0f / (float)N_;
        float mu = statsIn[tid] * nInv;
        float var = statsIn[128 + tid] * nInv - mu * mu;
        float sc = gamma[tid] * rsqrtf(var + BN_EPS);
        scale_s[tid] = sc;
        shift_s[tid] = beta[tid] - mu * sc;
    }
    __syncthreads();

    const int wave = tid >> 6;
    const int lane = tid & 63;
    const int m = lane & 15;
    const int quad = lane >> 4;
    const int rowBase = blockIdx.x * 128;
    const int r0 = rowBase + wave * 32 + m;       // sub-tile 0
    const int r1 = r0 + 16;                       // sub-tile 1
    const int a0 = r0 < nrows ? r0 : nrows - 1;
    const int a1 = r1 < nrows ? r1 : nrows - 1;

    floatx4 acc[2][8];
#pragma unroll
    for (int s = 0; s < 2; ++s)
#pragma unroll
        for (int i = 0; i < 8; ++i) acc[s][i] = (floatx4)0.f;

#pragma unroll
    for (int k0 = 0; k0 < 128; k0 += 32) {
        const int kb = k0 + quad * 8;
        short8 af[2];
        if (mode == 2) {
#pragma unroll
            for (int s = 0; s < 2; ++s) {
                const float* Af = (const float*)Ain + (size_t)(s ? a1 : a0) * 128 + kb;
                float4 x0 = *(const float4*)(Af);
                float4 x1 = *(const float4*)(Af + 4);
                af[s][0] = f2bf(x0.x); af[s][1] = f2bf(x0.y);
                af[s][2] = f2bf(x0.z); af[s][3] = f2bf(x0.w);
                af[s][4] = f2bf(x1.x); af[s][5] = f2bf(x1.y);
                af[s][6] = f2bf(x1.z); af[s][7] = f2bf(x1.w);
            }
        } else {
            af[0] = *(const short8*)((const short*)Ain + (size_t)a0 * 128 + kb);
            af[1] = *(const short8*)((const short*)Ain + (size_t)a1 * 128 + kb);
            if (mode == 1) {
                float4 sc0 = *(const float4*)&scale_s[kb];
                float4 sc1 = *(const float4*)&scale_s[kb + 4];
                float4 sh0 = *(const float4*)&shift_s[kb];
                float4 sh1 = *(const float4*)&shift_s[kb + 4];
#pragma unroll
                for (int s = 0; s < 2; ++s) {
                    af[s][0] = f2bf(fmaxf(fmaf(bf2f(af[s][0]), sc0.x, sh0.x), 0.f));
                    af[s][1] = f2bf(fmaxf(fmaf(bf2f(af[s][1]), sc0.y, sh0.y), 0.f));
                    af[s][2] = f2bf(fmaxf(fmaf(bf2f(af[s][2]), sc0.z, sh0.z), 0.f));
                    af[s][3] = f2bf(fmaxf(fmaf(bf2f(af[s][3]), sc0.w, sh0.w), 0.f));
                    af[s][4] = f2bf(fmaxf(fmaf(bf2f(af[s][4]), sc1.x, sh1.x), 0.f));
                    af[s][5] = f2bf(fmaxf(fmaf(bf2f(af[s][5]), sc1.y, sh1.y), 0.f));
                    af[s][6] = f2bf(fmaxf(fmaf(bf2f(af[s][6]), sc1.z, sh1.z), 0.f));
                    af[s][7] = f2bf(fmaxf(fmaf(bf2f(af[s][7]), sc1.w, sh1.w), 0.f));
                }
            }
        }
#pragma unroll
        for (int nt = 0; nt < 8; ++nt) {
            short8 bf = *(const short8*)&Bs[nt * 16 + m][kb];
            acc[0][nt] = __builtin_amdgcn_mfma_f32_16x16x32_bf16(af[0], bf, acc[0][nt], 0, 0, 0);
            acc[1][nt] = __builtin_amdgcn_mfma_f32_16x16x32_bf16(af[1], bf, acc[1][nt], 0, 0, 0);
        }
    }

    // Two-half epilogue through LDS (reuse Bs as fp32 C tile of 64 rows)
    float (*Cs)[132] = (float(*)[132])&Bs[0][0];   // 64*132*4 = 33792 B
    float S1 = 0.f, S2 = 0.f;
#pragma unroll
    for (int half = 0; half < 2; ++half) {
        __syncthreads();
        if ((wave >> 1) == half) {
            int wl = wave & 1;
#pragma unroll
            for (int nt = 0; nt < 8; ++nt) {
                float b = bias[nt * 16 + m];
#pragma unroll
                for (int s = 0; s < 2; ++s)
#pragma unroll
                    for (int r = 0; r < 4; ++r)
                        Cs[wl * 32 + s * 16 + quad * 4 + r][nt * 16 + m] = acc[s][nt][r] + b;
            }
        }
        __syncthreads();
        {
            int trow = tid >> 2;
            int tcg = (tid & 3) << 5;
            int grow = rowBase + half * 64 + trow;
            if (grow < nrows) {
                short* dst = Cout + (size_t)grow * 128 + tcg;
#pragma unroll
                for (int i = 0; i < 4; ++i) {
                    short8 o;
#pragma unroll
                    for (int j = 0; j < 8; ++j) o[j] = f2bf(Cs[trow][tcg + i * 8 + j]);
                    *(short8*)(dst + i * 8) = o;
                }
            }
        }
        if (tid < 128) {
            int nvalid = nrows - rowBase - half * 64;
            if (nvalid > 64) nvalid = 64;
            for (int r = 0; r < nvalid; ++r) {
                float v = Cs[r][tid];
                S1 += v; S2 += v * v;
            }
        }
    }
    if (tid < 128) {
        atomicAdd(&statsOut[tid], S1);
        atomicAdd(&statsOut[128 + tid], S2);
    }
}

// ---------------------------------------------------------------------------
// bn_pool: BN apply + ReLU + segment pool (no activation store).
// ---------------------------------------------------------------------------
__global__ __launch_bounds__(128) void bn_pool(
    const short* __restrict__ Cin, const float* __restrict__ stats,
    const float* __restrict__ gamma, const float* __restrict__ beta,
    const int* __restrict__ batch, float* __restrict__ pooled, int n)
{
    int c = threadIdx.x;
    const float nInv = 1.0f / (float)N_;
    float mu = stats[c] * nInv;
    float var = stats[128 + c] * nInv - mu * mu;
    float sc = gamma[c] * rsqrtf(var + BN_EPS);
    float sh = beta[c] - mu * sc;

    int per = (n + gridDim.x - 1) / gridDim.x;
    int r0 = blockIdx.x * per;
    int r1 = min(n, r0 + per);
    if (r0 >= r1) return;
    int curg = batch[r0];
    float s = 0.f;
    for (int r = r0; r < r1; ++r) {
        int g = batch[r];
        if (g != curg) {
            atomicAdd(&pooled[(size_t)curg * 128 + c], s);
            s = 0.f;
            curg = g;
        }
        s += fmaxf(fmaf(bf2f(Cin[(size_t)r * 128 + c]), sc, sh), 0.f);
    }
    atomicAdd(&pooled[(size_t)curg * 128 + c], s);
}

// ---------------------------------------------------------------------------
// aggregate: u[i] = (1+eps)*h[i] + sum_{j in N(i)} h[j] where
// h[r] = relu(bn(q[r])) applied inline (BN consts per lane's 2 columns).
// One wave per node; lane = 2 cols -> 256 B coalesced per neighbor row.
// ---------------------------------------------------------------------------
__global__ __launch_bounds__(256) void aggregate(
    const short* __restrict__ q, short* __restrict__ u,
    const int* __restrict__ off, const int* __restrict__ eidx,
    const float* __restrict__ stats, const float* __restrict__ gamma,
    const float* __restrict__ beta, const float* __restrict__ eps, int li)
{
    int node = blockIdx.x * 4 + (threadIdx.x >> 6);
    if (node >= N_) return;
    int lane = threadIdx.x & 63;
    int col = lane * 2;

    const float nInv = 1.0f / (float)N_;
    float mu0 = stats[col] * nInv;
    float mu1 = stats[col + 1] * nInv;
    float sc0 = gamma[col] * rsqrtf(stats[128 + col] * nInv - mu0 * mu0 + BN_EPS);
    float sc1 = gamma[col + 1] * rsqrtf(stats[128 + col + 1] * nInv - mu1 * mu1 + BN_EPS);
    float sh0 = beta[col] - mu0 * sc0;
    float sh1 = beta[col + 1] - mu1 * sc1;

    int s0 = off[node];
    int s1 = off[node + 1];
    float se = 1.0f + eps[li];

    ushort2 a = *(const ushort2*)(q + (size_t)node * 128 + col);
    float ax = fmaxf(fmaf(bf2f((short)a.x), sc0, sh0), 0.f) * se;
    float ay = fmaxf(fmaf(bf2f((short)a.y), sc1, sh1), 0.f) * se;

    int j = s0;
    for (; j + 3 < s1; j += 4) {
        int n0 = eidx[j], n1 = eidx[j + 1], n2 = eidx[j + 2], n3 = eidx[j + 3];
        ushort2 v0 = *(const ushort2*)(q + (size_t)n0 * 128 + col);
        ushort2 v1 = *(const ushort2*)(q + (size_t)n1 * 128 + col);
        ushort2 v2 = *(const ushort2*)(q + (size_t)n2 * 128 + col);
        ushort2 v3 = *(const ushort2*)(q + (size_t)n3 * 128 + col);
        ax += fmaxf(fmaf(bf2f((short)v0.x), sc0, sh0), 0.f)
            + fmaxf(fmaf(bf2f((short)v1.x), sc0, sh0), 0.f)
            + fmaxf(fmaf(bf2f((short)v2.x), sc0, sh0), 0.f)
            + fmaxf(fmaf(bf2f((short)v3.x), sc0, sh0), 0.f);
        ay += fmaxf(fmaf(bf2f((short)v0.y), sc1, sh1), 0.f)
            + fmaxf(fmaf(bf2f((short)v1.y), sc1, sh1), 0.f)
            + fmaxf(fmaf(bf2f((short)v2.y), sc1, sh1), 0.f)
            + fmaxf(fmaf(bf2f((short)v3.y), sc1, sh1), 0.f);
    }
    for (; j < s1; ++j) {
        int n0 = eidx[j];
        ushort2 v0 = *(const ushort2*)(q + (size_t)n0 * 128 + col);
        ax += fmaxf(fmaf(bf2f((short)v0.x), sc0, sh0), 0.f);
        ay += fmaxf(fmaf(bf2f((short)v0.y), sc1, sh1), 0.f);
    }
    ushort2 o;
    o.x = (unsigned short)f2bf(ax);
    o.y = (unsigned short)f2bf(ay);
    *(ushort2*)(u + (size_t)node * 128 + col) = o;
}

// ---------------------------------------------------------------------------
// out_final: out[g*T+t] = sigmoid(sum_l pooled_l[g]·Wl_l[:,t]/cnt_g + bl_l[t])
// ---------------------------------------------------------------------------
__global__ void out_final(const float* __restrict__ pooled,
                          const float* __restrict__ cntf,
                          const float* __restrict__ Wl,
                          const float* __restrict__ bl, float* __restrict__ out)
{
    int g = blockIdx.x;
    int t = threadIdx.x;
    if (t >= T_) return;
    float inv = 1.0f / fmaxf(cntf[g], 1.0f);
    float acc = 0.f;
#pragma unroll
    for (int l = 0; l < 4; ++l) {
        float s = 0.f;
        for (int c = 0; c < 128; ++c)
            s = fmaf(pooled[(size_t)l * (G_ * H_) + g * 128 + c],
                     Wl[(size_t)l * (H_ * T_) + c * T_ + t], s);
        acc += s * inv + bl[l * T_ + t];
    }
    out[g * T_ + t] = 1.0f / (1.0f + expf(-acc));
}

// ---------------------------------------------------------------------------
extern "C" void kernel_launch(void* const* d_in, const int* in_sizes, int n_in,
                              void* d_out, int out_size, void* d_ws, size_t ws_size,
                              hipStream_t stream)
{
    const float* x    = (const float*)d_in[0];
    const int*   ei   = (const int*)d_in[1];
    const int*   batch= (const int*)d_in[2];
    const float* Wa   = (const float*)d_in[3];
    const float* ba   = (const float*)d_in[4];
    const float* ga   = (const float*)d_in[5];
    const float* bea  = (const float*)d_in[6];
    const float* Wb   = (const float*)d_in[7];
    const float* bb   = (const float*)d_in[8];
    const float* gb   = (const float*)d_in[9];
    const float* beb  = (const float*)d_in[10];
    const float* Wl   = (const float*)d_in[11];
    const float* bl   = (const float*)d_in[12];
    const float* eps  = (const float*)d_in[13];
    float* out = (float*)d_out;

    const size_t NH = (size_t)N_ * H_;
    // workspace layout
    short* A   = (short*)d_ws;                 // N x H bf16
    short* B   = A + NH;                       // N x H bf16
    short* Wt  = B + NH;                       // 8 x 128 x 128 bf16
    float* stats  = (float*)(Wt + 8 * 16384);  // 8 x 256          [zeroed]
    float* pooled = stats + 8 * 256;           // 4 x G x 128      [zeroed]
    float* cntf   = pooled + 4 * (size_t)G_ * H_; // G  (written directly)
    int*   BH     = (int*)(cntf + G_);         // SCANN_ (written directly)
    int*   BHs    = BH + SCANN_;               // SCANN_
    int*   bsum   = BHs + SCANN_;              // 256
    int*   off    = bsum + 256;                // 100352 (>= N_+1)
    int2*  ebuf   = (int2*)(off + 100352);     // E
    int*   eidx   = (int*)(ebuf + E_);         // E

    const size_t zbytes = (size_t)(8 * 256 + 4 * G_ * H_) * 4;
    hipMemsetAsync(stats, 0, zbytes, stream);

    const int* esrc = ei;
    const int* edst = ei + E_;

    // ---- setup: weights, counts, CSR (bucket counting sort) ----
    convert_W<<<512, 256, 0, stream>>>(Wa, Wb, Wt);
    count_graphs<<<2, 256, 0, stream>>>(batch, cntf);
    edge_hist<<<NBLK_, 256, 0, stream>>>(edst, BH);
    scan1<<<SCANB_, 256, 0, stream>>>(BH, BHs, bsum, SCANN_);
    scan2<<<1, 256, 0, stream>>>(bsum, SCANB_);
    scan3<<<SCANB_, 256, 0, stream>>>(BHs, bsum, SCANN_);
    scatter_ebuf<<<NBLK_, 256, 0, stream>>>(esrc, edst, BHs, ebuf);
    fill_buckets<<<NB_, 256, 0, stream>>>(ebuf, BHs, eidx, off);

    const int gemmGrid = (N_ + 127) / 128;
    const int aggGrid = (N_ + 3) / 4;

    // ---- layer 0 ----
    gemm_mfma<<<gemmGrid, 256, 0, stream>>>(x, Wt, ba, A, stats,
                                            nullptr, nullptr, nullptr, 2, N_);
    gemm_mfma<<<gemmGrid, 256, 0, stream>>>(A, Wt + 4 * 16384, bb, B, stats + 256,
                                            stats, ga, bea, 1, N_);
    bn_pool<<<1024, 128, 0, stream>>>(B, stats + 256, gb, beb, batch, pooled, N_);

    // B holds pre-BN activation Q_{l-1}; alternate buffers each layer.
    short* Hbuf = B;   // pre-BN activation of previous layer
    short* Obuf = A;   // scratch
    for (int l = 1; l < 4; ++l) {
        float* stA = stats + (size_t)(2 * l) * 256;
        float* stB = stats + (size_t)(2 * l + 1) * 256;
        const float* stPrev = stats + (size_t)(2 * l - 1) * 256;
        // u = (1+eps)*relu(bn(q_self)) + sum relu(bn(q_nbr))   [inline BN]
        aggregate<<<aggGrid, 256, 0, stream>>>(Hbuf, Obuf, off, eidx,
                                               stPrev, gb + (l - 1) * H_,
                                               beb + (l - 1) * H_, eps, l - 1);
        gemm_mfma<<<gemmGrid, 256, 0, stream>>>(Obuf, Wt + (size_t)l * 16384,
                                                ba + l * H_, Hbuf, stA,
                                                nullptr, nullptr, nullptr, 0, N_);
        gemm_mfma<<<gemmGrid, 256, 0, stream>>>(Hbuf, Wt + (size_t)(4 + l) * 16384,
                                                bb + l * H_, Obuf, stB,
                                                stA, ga + l * H_, bea + l * H_, 1, N_);
        bn_pool<<<1024, 128, 0, stream>>>(Obuf, stB, gb + l * H_, beb + l * H_,
                                          batch, pooled + (size_t)l * G_ * H_, N_);
        // Obuf now holds this layer's pre-BN activation
        short* tmp = Hbuf; Hbuf = Obuf; Obuf = tmp;
    }

    out_final<<<G_, 64, 0, stream>>>(pooled, cntf, Wl, bl, out);
}